// Round 2
// 212.664 us; speedup vs baseline: 1.0854x; 1.0854x over previous
//
#include <hip/hip_runtime.h>
#include <hip/hip_bf16.h>

// VQ-VAE VectorQuantizer — round 7: resubmit of round-6 (infra failure) with
// widened rescore margin (TAU 0.2 -> 0.375).
//   Screen: S^T = (-2E)*X^T via 32x32x16 f16 MFMA, x split hi/lo fp16,
//           norms (+1024 bias) folded as 17th k-block.  Scores are positive ->
//           pack (bits(s) & ~1023) | code_idx, keep top-3 with a min/max
//           network (no serial cmp/cndmask chains).
//   Flag px whose top-2 gap < TAU (covers fp16 screen error + 10-bit trunc);
//   only those are exactly rescored (expected ~2-5% of px).
//   Loss = s1 - BIAS + ||x||^2 straight from the screen (exact for flagged).
//   Epilogue: no z read — gather chosen emb row (L2-hot), coalesced stores,
//   c-split x4 grid for occupancy; loss atomics pre-scaled (k_final fused).

#define EMBED_DIM 256
#define N_EMBED   1024
#define HW        4096
#define NPIX      65536
#define BETA      0.25f
#define SBIAS     1024.0f
#define TAU       0.375f

typedef _Float16 h8v __attribute__((ext_vector_type(8)));
typedef __attribute__((ext_vector_type(16))) float f32x16;

// ---------------- workspace layout (float offsets) ----------------
#define NW_LOSS   0       // fallback only
#define NW_NORMS  64      // fallback only
#define NW_CAND   1152    // 65536 int4 = 262144 floats
#define NW_ES2    263296  // 17*32*64 h8v = 278528 halves = 139264 floats
#define NW_END    402560
#define NEED_BYTES ((size_t)NW_END * 4)

// fallback (round-1) layout
#define WS_ET_OFF    64
#define WS_NORM_OFF  (64 + EMBED_DIM * N_EMBED)

#define CHUNK_BYTES (34 * 1024)   // 17 akb x 2 cb x 1 KB per chunk of 64 codes

__device__ inline void async16(const void* g, void* s) {
    __builtin_amdgcn_global_load_lds(
        (const __attribute__((address_space(1))) unsigned int*)g,
        (__attribute__((address_space(3))) unsigned int*)s, 16, 0, 0);
}

__device__ inline unsigned umin2(unsigned a, unsigned b) { return a < b ? a : b; }
__device__ inline unsigned umax2(unsigned a, unsigned b) { return a < b ? b : a; }

// sorted top-3 insert on packed (score|idx) — pure min/max network
__device__ inline void top3_ins(unsigned u, unsigned& b1, unsigned& b2, unsigned& b3) {
    unsigned t0 = umax2(b1, u);  b1 = umin2(b1, u);
    unsigned t1 = umax2(b2, t0); b2 = umin2(b2, t0);
    b3 = umin2(b3, t1);
}

// ======================= prep kernel =======================
// es2 frag t = (akb*32 + cb)*64 + lane ; akb 0-15 = fp16(-2e), 16 = norm kb.
// A layout: m = cb*32 + (lane&31), k = (lane>>5)*8 + j ; c = akb*16 + k.
// Norm kb encodes ||e||^2 + SBIAS (hi/lo fp16) so all scores are positive.
// Also zeroes the loss slot in out (epilogue atomics accumulate into it).

__global__ void k_prep_e2(const float* __restrict__ emb, _Float16* __restrict__ es2,
                          float* __restrict__ out_loss) {
    int t = blockIdx.x * 256 + threadIdx.x;       // 17*32*64 = 34816
    if (t == 0) *out_loss = 0.f;
    if (t >= 17 * 32 * 64) return;
    int lane = t & 63;
    int cb   = (t >> 6) & 31;
    int akb  = t >> 11;                           // 0..16
    int m = cb * 32 + (lane & 31);
    int h = lane >> 5;
    _Float16 o[8];
    if (akb < 16) {
        #pragma unroll
        for (int j = 0; j < 8; ++j) {
            int c = akb * 16 + h * 8 + j;
            o[j] = (_Float16)(-2.0f * emb[m * EMBED_DIM + c]);
        }
    } else {
        #pragma unroll
        for (int j = 0; j < 8; ++j) o[j] = (_Float16)0.f;
        if (h == 0) {                             // inline norm (k_norms fused)
            const float4* row = (const float4*)(emb + (size_t)m * EMBED_DIM);
            float nm = SBIAS;
            #pragma unroll 8
            for (int r = 0; r < 64; ++r) {
                float4 v = row[r];
                nm += v.x * v.x + v.y * v.y + v.z * v.z + v.w * v.w;
            }
            _Float16 nh = (_Float16)nm;
            _Float16 nl = (_Float16)(nm - (float)nh);
            o[0] = nh; o[1] = nl;
        }
    }
    *(h8v*)(es2 + (size_t)t * 8) = *(h8v*)o;
}

// ======================= screen kernel =======================
// 512 threads (8 waves), 256 px/block, grid 256. LDS double-buffers the
// per-chunk A fragments (34 KB each). 16 chunks of 64 codes.

__global__ __launch_bounds__(512, 2)
void k_screen3(const float* __restrict__ z, const _Float16* __restrict__ es2,
               int4* __restrict__ cand) {
    __shared__ __align__(16) char abuf[2 * CHUNK_BYTES];   // 68 KB

    const int tid  = threadIdx.x;
    const int lane = tid & 63;
    const int wv   = tid >> 6;                    // 0..7
    const int pxl  = lane & 31;
    const int h    = lane >> 5;
    const int ln16 = lane * 16;

    // kick off staging of chunk 0
    {
        char* bufn = abuf;
        for (int f = wv; f < 34; f += 8) {
            const _Float16* src = es2 + ((size_t)((f >> 1) * 32 + (f & 1)) * 64 + lane) * 8;
            async16(src, bufn + f * 1024 + ln16);
        }
    }

    // build B fragments (this wave's 32 pixels) straight from z; accumulate ||x||^2
    const int px = blockIdx.x * 256 + wv * 32 + pxl;
    const int b = px >> 12, hw = px & 4095;
    const float* zb = z + (size_t)b * (EMBED_DIM * HW) + hw;

    float nx = 0.f;
    h8v bx[32];                                   // [0..15]=xh, [16..31]=xl
    #pragma unroll
    for (int kh = 0; kh < 16; ++kh) {
        const int c0 = kh * 16 + h * 8;
        _Float16 oh[8], ol[8];
        #pragma unroll
        for (int j = 0; j < 8; ++j) {
            float v = zb[(size_t)(c0 + j) * HW];
            nx += v * v;
            _Float16 hv = (_Float16)v;
            oh[j] = hv;
            ol[j] = (_Float16)(v - (float)hv);
        }
        bx[kh]      = *(h8v*)oh;
        bx[16 + kh] = *(h8v*)ol;
    }
    nx += __shfl_xor(nx, 32, 64);                 // full ||x||^2 on both halves

    h8v bn;                                       // norm-kb B: B[0..1][n] = 1
    #pragma unroll
    for (int j = 0; j < 8; ++j) bn[j] = (_Float16)0.f;
    if (lane < 32) { bn[0] = (_Float16)1.f; bn[1] = (_Float16)1.f; }

    const int h4 = h * 4;
    unsigned b1 = 0xFFFFFFFFu, b2 = 0xFFFFFFFFu, b3 = 0xFFFFFFFFu;

    __syncthreads();                              // chunk-0 staging complete

    for (int c = 0; c < 16; ++c) {
        if (c + 1 < 16) {                         // stage next chunk (overlapped)
            char* bufn = abuf + ((c + 1) & 1) * CHUNK_BYTES;
            for (int f = wv; f < 34; f += 8) {
                const _Float16* src = es2 +
                    ((size_t)((f >> 1) * 32 + (c + 1) * 2 + (f & 1)) * 64 + lane) * 8;
                async16(src, bufn + f * 1024 + ln16);
            }
        }

        const char* bufc = abuf + (c & 1) * CHUNK_BYTES;
        f32x16 acc0, acc1;
        #pragma unroll
        for (int r = 0; r < 16; ++r) { acc0[r] = 0.f; acc1[r] = 0.f; }

        // software-pipelined A-frag loads: prefetch akb+1 while computing akb
        h8v a0 = *(const h8v*)(bufc + 0 * 1024 + ln16);
        h8v a1 = *(const h8v*)(bufc + 1 * 1024 + ln16);
        #pragma unroll
        for (int akb = 0; akb < 16; ++akb) {
            h8v n0 = *(const h8v*)(bufc + ((akb + 1) * 2 + 0) * 1024 + ln16);
            h8v n1 = *(const h8v*)(bufc + ((akb + 1) * 2 + 1) * 1024 + ln16);
            acc0 = __builtin_amdgcn_mfma_f32_32x32x16_f16(a0, bx[akb], acc0, 0, 0, 0);
            acc1 = __builtin_amdgcn_mfma_f32_32x32x16_f16(a1, bx[akb], acc1, 0, 0, 0);
            acc0 = __builtin_amdgcn_mfma_f32_32x32x16_f16(a0, bx[16 + akb], acc0, 0, 0, 0);
            acc1 = __builtin_amdgcn_mfma_f32_32x32x16_f16(a1, bx[16 + akb], acc1, 0, 0, 0);
            a0 = n0; a1 = n1;
        }
        // norm+bias kb (akb == 16)
        acc0 = __builtin_amdgcn_mfma_f32_32x32x16_f16(a0, bn, acc0, 0, 0, 0);
        acc1 = __builtin_amdgcn_mfma_f32_32x32x16_f16(a1, bn, acc1, 0, 0, 0);

        // packed top-3 update; C/D: col(px)=lane&31, row=(r&3)+8*(r>>2)+4*(lane>>5)
        const unsigned jb = (unsigned)(c * 64 + h4);
        #pragma unroll
        for (int r = 0; r < 16; ++r) {
            const unsigned row = (unsigned)((r & 3) + 8 * (r >> 2));
            unsigned u0 = (__float_as_uint(acc0[r]) & 0xFFFFFC00u) | (jb + row);
            unsigned u1 = (__float_as_uint(acc1[r]) & 0xFFFFFC00u) | (jb + row + 32u);
            top3_ins(u0, b1, b2, b3);
            top3_ins(u1, b1, b2, b3);
        }

        __syncthreads();   // drains staging; guards buffer reuse
    }

    // merge the two k-row halves (lane^32 holds the other 16 rows per block)
    {
        unsigned o1 = __shfl_xor(b1, 32, 64);
        unsigned o2 = __shfl_xor(b2, 32, 64);
        unsigned o3 = __shfl_xor(b3, 32, 64);
        top3_ins(o1, b1, b2, b3);
        top3_ins(o2, b1, b2, b3);
        top3_ins(o3, b1, b2, b3);
    }

    if (lane < 32) {
        float s1 = __uint_as_float(b1 & 0xFFFFFC00u);
        float s2 = __uint_as_float(b2 & 0xFFFFFC00u);
        int  flag = (s2 - s1 < TAU) ? 0x10000 : 0;
        float d  = s1 - SBIAS + nx;               // screen-accurate distance (loss)
        cand[px] = make_int4((int)(b1 & 1023u),
                             (int)((b2 & 1023u) | flag),
                             (int)(b3 & 1023u),
                             __float_as_int(d));
    }
}

// ======================= epilogue =======================
// Scatter-only: no z read except for rare flagged px. Grid = 1024 blocks
// (256 px-blocks x 4 c-quarters) x 256 threads, 1 px/thread.

__global__ __launch_bounds__(256)
void k_epi2(const float* __restrict__ z, const float* __restrict__ emb,
            const int4* __restrict__ cand, float* __restrict__ out,
            float* __restrict__ out_loss) {
    const int tid   = threadIdx.x;
    const int lane  = tid & 63;
    const int pxblk = blockIdx.x >> 2;
    const int cq    = blockIdx.x & 3;
    const int px = pxblk * 256 + tid;
    const int b = px >> 12, hw = px & 4095;

    const int4 cd = cand[px];
    int   j = cd.x;
    float d = __int_as_float(cd.w);

    // rare exact rescore of flagged (near-tie) pixels — wave-cooperative
    unsigned long long fm = __ballot((cd.y & 0x10000) != 0);
    if (fm) {
        const int pxw = pxblk * 256 + (tid & ~63);   // wave's first px
        while (fm) {
            const int l = __ffsll(fm) - 1;
            fm &= fm - 1;
            const int fj1 = __shfl(cd.x, l, 64);
            const int fj2 = __shfl(cd.y, l, 64) & 1023;
            const int fj3 = __shfl(cd.z, l, 64);
            const int fpx = pxw + l;
            const float* zp = z + (size_t)(fpx >> 12) * (EMBED_DIM * HW) + (fpx & 4095);
            const int c0 = lane * 4;
            const float4 e1 = *(const float4*)(emb + (size_t)fj1 * EMBED_DIM + c0);
            const float4 e2 = *(const float4*)(emb + (size_t)fj2 * EMBED_DIM + c0);
            const float4 e3 = *(const float4*)(emb + (size_t)fj3 * EMBED_DIM + c0);
            float d1 = 0.f, d2 = 0.f, d3 = 0.f;
            #pragma unroll
            for (int k = 0; k < 4; ++k) {
                const float zv = zp[(size_t)(c0 + k) * HW];
                float t1 = ((const float*)&e1)[k] - zv; d1 += t1 * t1;
                float t2 = ((const float*)&e2)[k] - zv; d2 += t2 * t2;
                float t3 = ((const float*)&e3)[k] - zv; d3 += t3 * t3;
            }
            #pragma unroll
            for (int off = 32; off; off >>= 1) {
                d1 += __shfl_xor(d1, off, 64);
                d2 += __shfl_xor(d2, off, 64);
                d3 += __shfl_xor(d3, off, 64);
            }
            int bj = fj1; float bd = d1;
            if (d2 < bd || (d2 == bd && fj2 < bj)) { bd = d2; bj = fj2; }
            if (d3 < bd || (d3 == bd && fj3 < bj)) { bd = d3; bj = fj3; }
            if (lane == l) { j = bj; d = bd; }
        }
    }

    // write this c-quarter of the chosen embedding row (emb is L2-resident)
    const float* er = emb + (size_t)j * EMBED_DIM + cq * 64;
    float* ob = out + (size_t)b * (EMBED_DIM * HW) + (size_t)(cq * 64) * HW + hw;
    #pragma unroll
    for (int q = 0; q < 16; ++q) {
        const float4 e4 = *(const float4*)(er + q * 4);
        ob[(size_t)(q * 4 + 0) * HW] = e4.x;
        ob[(size_t)(q * 4 + 1) * HW] = e4.y;
        ob[(size_t)(q * 4 + 2) * HW] = e4.z;
        ob[(size_t)(q * 4 + 3) * HW] = e4.w;
    }

    if (cq == 0) {                                 // loss (k_final fused: pre-scaled)
        float ls = d;
        #pragma unroll
        for (int off = 32; off; off >>= 1) ls += __shfl_xor(ls, off, 64);
        if (lane == 0)
            atomicAdd(out_loss, ls * (BETA / (float)NPIX / (float)EMBED_DIM));
    }
}

// ======================= fallback (round-1 fp32 path) =======================

__global__ void k_norms(const float* __restrict__ emb, float* __restrict__ norms,
                        float* __restrict__ loss_acc) {
    int j = blockIdx.x;
    int lane = threadIdx.x;
    const float* row = emb + j * EMBED_DIM;
    float s = 0.f;
    #pragma unroll
    for (int r = 0; r < 4; ++r) { float v = row[lane + r * 64]; s += v * v; }
    #pragma unroll
    for (int off = 32; off; off >>= 1) s += __shfl_down(s, off, 64);
    if (lane == 0) norms[j] = s;
    if (blockIdx.x == 0 && lane == 0) loss_acc[0] = 0.f;
}

__global__ void k_final(const float* __restrict__ loss_acc, float* __restrict__ out_loss) {
    *out_loss = (BETA / (float)NPIX / (float)EMBED_DIM) * (*loss_acc);
}

__global__ void k_transpose(const float* __restrict__ emb, float* __restrict__ et) {
    int idx = blockIdx.x * blockDim.x + threadIdx.x;
    int c = idx >> 10;
    int j = idx & 1023;
    et[idx] = -2.0f * emb[j * EMBED_DIM + c];
}

__global__ __launch_bounds__(256, 2)
void k_vq(const float* __restrict__ z, const float* __restrict__ emb,
          const float* __restrict__ et, const float* __restrict__ norms,
          float* __restrict__ out, float* __restrict__ loss_acc)
{
    __shared__ float zt[EMBED_DIM * 64];
    __shared__ float redv[16 * 64];
    __shared__ int   redi[16 * 64];
    __shared__ int   widx[64];
    __shared__ float wsum[4];
    const int tid = threadIdx.x;
    const int wg  = blockIdx.x;
    const int p0  = wg * 64;
    const int b   = p0 >> 12;
    const int hw0 = p0 & 4095;
    const float* zbase = z + (size_t)b * (EMBED_DIM * HW) + hw0;
    {
        const int lane16 = tid & 15;
        const int crow   = tid >> 4;
        #pragma unroll
        for (int r = 0; r < 16; ++r) {
            int c = r * 16 + crow;
            float4 vv = *(const float4*)(zbase + (size_t)c * HW + lane16 * 4);
            *(float4*)&zt[c * 64 + lane16 * 4] = vv;
        }
    }
    __syncthreads();
    const int pxg = tid & 15;
    const int cg  = tid >> 4;
    float bestv[4] = {3.4e38f, 3.4e38f, 3.4e38f, 3.4e38f};
    int   besti[4] = {0, 0, 0, 0};
    for (int chunk = 0; chunk < 16; ++chunk) {
        const int jbase = chunk * 64 + cg * 4;
        float acc[4][4];
        #pragma unroll
        for (int i = 0; i < 4; ++i)
            #pragma unroll
            for (int k = 0; k < 4; ++k) acc[i][k] = 0.f;
        const float* ec = et + jbase;
        #pragma unroll 4
        for (int c = 0; c < EMBED_DIM; ++c) {
            float4 za = *(const float4*)&zt[c * 64 + pxg * 4];
            float4 eb = *(const float4*)(ec + (size_t)c * N_EMBED);
            float zi[4] = {za.x, za.y, za.z, za.w};
            float ek[4] = {eb.x, eb.y, eb.z, eb.w};
            #pragma unroll
            for (int i = 0; i < 4; ++i)
                #pragma unroll
                for (int k = 0; k < 4; ++k)
                    acc[i][k] += zi[i] * ek[k];
        }
        float nn[4];
        #pragma unroll
        for (int k = 0; k < 4; ++k) nn[k] = norms[jbase + k];
        #pragma unroll
        for (int i = 0; i < 4; ++i)
            #pragma unroll
            for (int k = 0; k < 4; ++k) {
                float s = nn[k] + acc[i][k];
                if (s < bestv[i]) { bestv[i] = s; besti[i] = jbase + k; }
            }
    }
    #pragma unroll
    for (int i = 0; i < 4; ++i) {
        redv[cg * 64 + pxg * 4 + i] = bestv[i];
        redi[cg * 64 + pxg * 4 + i] = besti[i];
    }
    __syncthreads();
    if (tid < 64) {
        const int px2 = tid;
        float bv = redv[px2];
        int   bi = redi[px2];
        #pragma unroll
        for (int g = 1; g < 16; ++g) {
            float vv = redv[g * 64 + px2];
            int   ix = redi[g * 64 + px2];
            if (vv < bv || (vv == bv && ix < bi)) { bv = vv; bi = ix; }
        }
        widx[px2] = bi;
    }
    __syncthreads();
    const int px = tid & 63;
    const int wv = tid >> 6;
    const int j  = widx[px];
    const float* qrow = emb + (size_t)j * EMBED_DIM;
    float* obase = out + (size_t)b * (EMBED_DIM * HW) + hw0;
    float lsum = 0.f;
    #pragma unroll 4
    for (int cc = 0; cc < 16; ++cc) {
        const int c0 = wv * 64 + cc * 4;
        float4 q = *(const float4*)(qrow + c0);
        float qv[4] = {q.x, q.y, q.z, q.w};
        #pragma unroll
        for (int k = 0; k < 4; ++k) {
            const int c = c0 + k;
            float zv = zt[c * 64 + px];
            float d = qv[k] - zv;
            lsum += d * d;
            obase[(size_t)c * HW + px] = qv[k];
        }
    }
    #pragma unroll
    for (int off = 32; off; off >>= 1) lsum += __shfl_down(lsum, off, 64);
    if ((tid & 63) == 0) wsum[wv] = lsum;
    __syncthreads();
    if (tid == 0) atomicAdd(loss_acc, wsum[0] + wsum[1] + wsum[2] + wsum[3]);
}

// ======================= launch =======================

extern "C" void kernel_launch(void* const* d_in, const int* in_sizes, int n_in,
                              void* d_out, int out_size, void* d_ws, size_t ws_size,
                              hipStream_t stream) {
    const float* z   = (const float*)d_in[0];
    const float* emb = (const float*)d_in[1];
    float* out       = (float*)d_out;
    float* ws        = (float*)d_ws;

    if (ws_size >= NEED_BYTES) {
        int4*      cand     = (int4*)(ws + NW_CAND);
        _Float16*  es2      = (_Float16*)(ws + NW_ES2);
        float*     out_loss = out + (size_t)NPIX * EMBED_DIM;

        k_prep_e2<<<136, 256, 0, stream>>>(emb, es2, out_loss);
        k_screen3<<<256, 512, 0, stream>>>(z, es2, cand);
        k_epi2<<<1024, 256, 0, stream>>>(z, emb, cand, out, out_loss);
    } else {
        float* loss_acc = ws;
        float* et       = ws + WS_ET_OFF;
        float* norms    = ws + WS_NORM_OFF;
        k_transpose<<<(EMBED_DIM * N_EMBED) / 256, 256, 0, stream>>>(emb, et);
        k_norms<<<N_EMBED, 64, 0, stream>>>(emb, norms, loss_acc);
        k_vq<<<NPIX / 64, 256, 0, stream>>>(z, emb, et, norms, out, loss_acc);
        k_final<<<1, 1, 0, stream>>>(loss_acc, out + (size_t)NPIX * EMBED_DIM);
    }
}

// Round 3
// 197.500 us; speedup vs baseline: 1.1688x; 1.0768x over previous
//
#include <hip/hip_runtime.h>
#include <hip/hip_bf16.h>

// VQ-VAE VectorQuantizer — round 8: occupancy + streaming restructure.
//   k_prep2  : es2 A-frags (fp16 -2e + norm/bias kb) + embT[c][j] transpose.
//   k_screen5: code-split screen — 512 blocks = (256 px-blocks) x (2 code
//              halves of 512 codes). Hi-only fp16 x (error << TAU; exact
//              rescore covers). Packed top-3 per half -> cand2[2][px].
//   k_res    : merge halves, flag gap<TAU, exact rescore flagged px (only z
//              reads), emit u16 widx[px] + full loss (1 atomic/block).
//   k_epi3   : one wave per out row (b,c): widx slice + embT row gathers
//              (L1-hot), contiguous float4 row stores. Pure streaming.

#define EMBED_DIM 256
#define N_EMBED   1024
#define HW        4096
#define NPIX      65536
#define BETA      0.25f
#define SBIAS     1024.0f
#define TAU       0.375f

typedef _Float16 h8v __attribute__((ext_vector_type(8)));
typedef __attribute__((ext_vector_type(16))) float f32x16;

// ---------------- new-path workspace layout (float offsets) ----------------
#define NW_CAND2  1152            // 2*65536 int4 = 524288 floats
#define NW_ES2B   525440          // 17*32*64 h8v = 139264 floats
#define NW_WIDX   525440          // u16[65536] aliases es2 (dead after screen)
#define NW_EMBT   664704          // 256*1024 floats
#define NW_END2   926848
#define NEED2_BYTES ((size_t)NW_END2 * 4)

// ---------------- round-7 (middle tier) layout ----------------
#define NW_CAND   1152
#define NW_ES2    263296
#define NW_END    402560
#define NEED_BYTES ((size_t)NW_END * 4)

// fallback (round-1) layout
#define WS_ET_OFF    64
#define WS_NORM_OFF  (64 + EMBED_DIM * N_EMBED)

#define CHUNK_BYTES (34 * 1024)   // 17 akb x 2 cb x 1 KB per chunk of 64 codes

__device__ inline void async16(const void* g, void* s) {
    __builtin_amdgcn_global_load_lds(
        (const __attribute__((address_space(1))) unsigned int*)g,
        (__attribute__((address_space(3))) unsigned int*)s, 16, 0, 0);
}

__device__ inline unsigned umin2(unsigned a, unsigned b) { return a < b ? a : b; }
__device__ inline unsigned umax2(unsigned a, unsigned b) { return a < b ? b : a; }

// sorted top-3 insert on packed (score|idx) — pure min/max network
__device__ inline void top3_ins(unsigned u, unsigned& b1, unsigned& b2, unsigned& b3) {
    unsigned t0 = umax2(b1, u);  b1 = umin2(b1, u);
    unsigned t1 = umax2(b2, t0); b2 = umin2(b2, t0);
    b3 = umin2(b3, t1);
}

// ======================= prep kernel (new path) =======================
// blocks 0..135   : es2 frag t = (akb*32 + cb)*64 + lane ; akb 16 = norm kb
//                   (||e||^2 + SBIAS as fp16 hi/lo in k=0,1).
// blocks 136..1159: embT[c][j] = emb[j][c].

__global__ void k_prep2(const float* __restrict__ emb, _Float16* __restrict__ es2,
                        float* __restrict__ embT, float* __restrict__ out_loss) {
    if (blockIdx.x < 136) {
        int t = blockIdx.x * 256 + threadIdx.x;       // 0..34815
        if (t == 0) *out_loss = 0.f;
        int lane = t & 63;
        int cb   = (t >> 6) & 31;
        int akb  = t >> 11;                           // 0..16
        int m = cb * 32 + (lane & 31);
        int h = lane >> 5;
        _Float16 o[8];
        if (akb < 16) {
            #pragma unroll
            for (int j = 0; j < 8; ++j) {
                int c = akb * 16 + h * 8 + j;
                o[j] = (_Float16)(-2.0f * emb[m * EMBED_DIM + c]);
            }
        } else {
            #pragma unroll
            for (int j = 0; j < 8; ++j) o[j] = (_Float16)0.f;
            if (h == 0) {                             // inline norm
                const float4* row = (const float4*)(emb + (size_t)m * EMBED_DIM);
                float nm = SBIAS;
                #pragma unroll 8
                for (int r = 0; r < 64; ++r) {
                    float4 v = row[r];
                    nm += v.x * v.x + v.y * v.y + v.z * v.z + v.w * v.w;
                }
                _Float16 nh = (_Float16)nm;
                _Float16 nl = (_Float16)(nm - (float)nh);
                o[0] = nh; o[1] = nl;
            }
        }
        *(h8v*)(es2 + (size_t)t * 8) = *(h8v*)o;
    } else {
        int t2 = (blockIdx.x - 136) * 256 + threadIdx.x;   // 0..262143
        int j = t2 & 1023;
        int c = t2 >> 10;
        embT[t2] = emb[(size_t)j * EMBED_DIM + c];
    }
}

// ======================= screen kernel (new path) =======================
// 512 threads (8 waves). blockIdx = pxblk*2 + half; scans codes
// [half*512, half*512+512) for 256 px. 8 chunks of 64 codes, dbuf LDS.
// Hi-only fp16 x. Writes packed top-3 + bits(nx) to cand2[half][px].

__global__ __launch_bounds__(512, 4)
void k_screen5(const float* __restrict__ z, const _Float16* __restrict__ es2,
               int4* __restrict__ cand2) {
    __shared__ __align__(16) char abuf[2 * CHUNK_BYTES];   // 68 KB

    const int tid  = threadIdx.x;
    const int lane = tid & 63;
    const int wv   = tid >> 6;                    // 0..7
    const int pxl  = lane & 31;
    const int h    = lane >> 5;
    const int ln16 = lane * 16;
    const int pxblk = blockIdx.x >> 1;
    const int half  = blockIdx.x & 1;
    const int gc0   = half * 8;                   // first global chunk

    // kick off staging of chunk 0
    {
        char* bufn = abuf;
        for (int f = wv; f < 34; f += 8) {
            const _Float16* src = es2 +
                ((size_t)((f >> 1) * 32 + gc0 * 2 + (f & 1)) * 64 + lane) * 8;
            async16(src, bufn + f * 1024 + ln16);
        }
    }

    // build B fragments (hi-only) straight from z; accumulate ||x||^2
    const int px = pxblk * 256 + wv * 32 + pxl;
    const int b = px >> 12, hw = px & 4095;
    const float* zb = z + (size_t)b * (EMBED_DIM * HW) + hw;

    float nx = 0.f;
    h8v bx[16];
    #pragma unroll
    for (int kh = 0; kh < 16; ++kh) {
        const int c0 = kh * 16 + h * 8;
        _Float16 oh[8];
        #pragma unroll
        for (int j = 0; j < 8; ++j) {
            float v = zb[(size_t)(c0 + j) * HW];
            nx += v * v;
            oh[j] = (_Float16)v;
        }
        bx[kh] = *(h8v*)oh;
    }
    nx += __shfl_xor(nx, 32, 64);                 // full ||x||^2 on both halves

    h8v bn;                                       // norm-kb B: B[0..1][n] = 1
    #pragma unroll
    for (int j = 0; j < 8; ++j) bn[j] = (_Float16)0.f;
    if (lane < 32) { bn[0] = (_Float16)1.f; bn[1] = (_Float16)1.f; }

    const int h4 = h * 4;
    unsigned b1 = 0xFFFFFFFFu, b2 = 0xFFFFFFFFu, b3 = 0xFFFFFFFFu;

    __syncthreads();                              // chunk-0 staging complete

    for (int c = 0; c < 8; ++c) {
        if (c + 1 < 8) {                          // stage next chunk (overlapped)
            char* bufn = abuf + ((c + 1) & 1) * CHUNK_BYTES;
            const int gcn = gc0 + c + 1;
            for (int f = wv; f < 34; f += 8) {
                const _Float16* src = es2 +
                    ((size_t)((f >> 1) * 32 + gcn * 2 + (f & 1)) * 64 + lane) * 8;
                async16(src, bufn + f * 1024 + ln16);
            }
        }

        const char* bufc = abuf + (c & 1) * CHUNK_BYTES;
        f32x16 acc0, acc1;
        #pragma unroll
        for (int r = 0; r < 16; ++r) { acc0[r] = 0.f; acc1[r] = 0.f; }

        // software-pipelined A-frag loads
        h8v a0 = *(const h8v*)(bufc + 0 * 1024 + ln16);
        h8v a1 = *(const h8v*)(bufc + 1 * 1024 + ln16);
        #pragma unroll
        for (int akb = 0; akb < 16; ++akb) {
            h8v n0 = *(const h8v*)(bufc + ((akb + 1) * 2 + 0) * 1024 + ln16);
            h8v n1 = *(const h8v*)(bufc + ((akb + 1) * 2 + 1) * 1024 + ln16);
            acc0 = __builtin_amdgcn_mfma_f32_32x32x16_f16(a0, bx[akb], acc0, 0, 0, 0);
            acc1 = __builtin_amdgcn_mfma_f32_32x32x16_f16(a1, bx[akb], acc1, 0, 0, 0);
            a0 = n0; a1 = n1;
        }
        // norm+bias kb (akb == 16)
        acc0 = __builtin_amdgcn_mfma_f32_32x32x16_f16(a0, bn, acc0, 0, 0, 0);
        acc1 = __builtin_amdgcn_mfma_f32_32x32x16_f16(a1, bn, acc1, 0, 0, 0);

        // packed top-3; C/D: col(px)=lane&31, row=(r&3)+8*(r>>2)+4*(lane>>5)
        const unsigned jb = (unsigned)((gc0 + c) * 64 + h4);
        #pragma unroll
        for (int r = 0; r < 16; ++r) {
            const unsigned row = (unsigned)((r & 3) + 8 * (r >> 2));
            unsigned u0 = (__float_as_uint(acc0[r]) & 0xFFFFFC00u) | (jb + row);
            unsigned u1 = (__float_as_uint(acc1[r]) & 0xFFFFFC00u) | (jb + row + 32u);
            top3_ins(u0, b1, b2, b3);
            top3_ins(u1, b1, b2, b3);
        }

        __syncthreads();   // drains staging; guards buffer reuse
    }

    // merge the two k-row halves (lane^32 holds the other 16 rows per block)
    {
        unsigned o1 = __shfl_xor(b1, 32, 64);
        unsigned o2 = __shfl_xor(b2, 32, 64);
        unsigned o3 = __shfl_xor(b3, 32, 64);
        top3_ins(o1, b1, b2, b3);
        top3_ins(o2, b1, b2, b3);
        top3_ins(o3, b1, b2, b3);
    }

    if (lane < 32)
        cand2[(half << 16) + px] =
            make_int4((int)b1, (int)b2, (int)b3, __float_as_int(nx));
}

// ======================= resolve kernel =======================
// Merge per-half top-3, flag gap<TAU, exact rescore flagged px (wave-coop),
// emit widx[px] (u16) + loss (one pre-scaled atomic per block).

__global__ __launch_bounds__(256)
void k_res(const float* __restrict__ z, const float* __restrict__ emb,
           const int4* __restrict__ cand2, unsigned short* __restrict__ widx,
           float* __restrict__ out_loss) {
    __shared__ float wsum[4];
    const int tid  = threadIdx.x;
    const int lane = tid & 63;
    const int wv   = tid >> 6;
    const int px   = blockIdx.x * 256 + tid;

    const int4 A = cand2[px];
    const int4 B = cand2[65536 + px];

    unsigned m1 = 0xFFFFFFFFu, m2 = 0xFFFFFFFFu, m3 = 0xFFFFFFFFu;
    top3_ins((unsigned)A.x, m1, m2, m3);
    top3_ins((unsigned)A.y, m1, m2, m3);
    top3_ins((unsigned)A.z, m1, m2, m3);
    top3_ins((unsigned)B.x, m1, m2, m3);
    top3_ins((unsigned)B.y, m1, m2, m3);
    top3_ins((unsigned)B.z, m1, m2, m3);

    const float s1 = __uint_as_float(m1 & 0xFFFFFC00u);
    const float s2 = __uint_as_float(m2 & 0xFFFFFC00u);
    const float nx = __int_as_float(A.w);
    int   j = (int)(m1 & 1023u);
    float d = s1 - SBIAS + nx;                     // screen-accurate distance
    const int j2 = (int)(m2 & 1023u);
    const int j3 = (int)(m3 & 1023u);

    // rare exact rescore of flagged (near-tie) pixels — wave-cooperative
    unsigned long long fm = __ballot(s2 - s1 < TAU);
    if (fm) {
        const int pxw = blockIdx.x * 256 + (tid & ~63);   // wave's first px
        while (fm) {
            const int l = __ffsll(fm) - 1;
            fm &= fm - 1;
            const int fj1 = __shfl(j, l, 64);
            const int fj2 = __shfl(j2, l, 64);
            const int fj3 = __shfl(j3, l, 64);
            const int fpx = pxw + l;
            const float* zp = z + (size_t)(fpx >> 12) * (EMBED_DIM * HW) + (fpx & 4095);
            const int c0 = lane * 4;
            const float4 e1 = *(const float4*)(emb + (size_t)fj1 * EMBED_DIM + c0);
            const float4 e2 = *(const float4*)(emb + (size_t)fj2 * EMBED_DIM + c0);
            const float4 e3 = *(const float4*)(emb + (size_t)fj3 * EMBED_DIM + c0);
            float d1 = 0.f, d2 = 0.f, d3 = 0.f;
            #pragma unroll
            for (int k = 0; k < 4; ++k) {
                const float zv = zp[(size_t)(c0 + k) * HW];
                float t1 = ((const float*)&e1)[k] - zv; d1 += t1 * t1;
                float t2 = ((const float*)&e2)[k] - zv; d2 += t2 * t2;
                float t3 = ((const float*)&e3)[k] - zv; d3 += t3 * t3;
            }
            #pragma unroll
            for (int off = 32; off; off >>= 1) {
                d1 += __shfl_xor(d1, off, 64);
                d2 += __shfl_xor(d2, off, 64);
                d3 += __shfl_xor(d3, off, 64);
            }
            int bj = fj1; float bd = d1;
            if (d2 < bd || (d2 == bd && fj2 < bj)) { bd = d2; bj = fj2; }
            if (d3 < bd || (d3 == bd && fj3 < bj)) { bd = d3; bj = fj3; }
            if (lane == l) { j = bj; d = bd; }
        }
    }

    widx[px] = (unsigned short)j;

    float ls = d;
    #pragma unroll
    for (int off = 32; off; off >>= 1) ls += __shfl_xor(ls, off, 64);
    if (lane == 0) wsum[wv] = ls;
    __syncthreads();
    if (tid == 0)
        atomicAdd(out_loss, (wsum[0] + wsum[1] + wsum[2] + wsum[3]) *
                            (BETA / (float)NPIX / (float)EMBED_DIM));
}

// ======================= streaming epilogue =======================
// One wave per out row (b,c): 16 KB contiguous stores; gathers from the
// L1-hot embT row (4 KB) + widx slice (8 KB).

__global__ __launch_bounds__(256)
void k_epi3(const float* __restrict__ embT, const unsigned short* __restrict__ widx,
            float* __restrict__ out) {
    const int tid  = threadIdx.x;
    const int lane = tid & 63;
    const int wv   = tid >> 6;
    const int rowid = blockIdx.x * 4 + wv;        // 0..4095
    const int b = rowid >> 8;
    const int c = rowid & 255;

    const unsigned short* wb = widx + b * HW;
    const float* et = embT + (size_t)c * N_EMBED;
    float* ob = out + (size_t)b * (EMBED_DIM * HW) + (size_t)c * HW;

    #pragma unroll 4
    for (int t = 0; t < 16; ++t) {
        const int hw = t * 256 + lane * 4;
        const ushort4 jj = *(const ushort4*)(wb + hw);
        float4 v;
        v.x = et[jj.x];
        v.y = et[jj.y];
        v.z = et[jj.z];
        v.w = et[jj.w];
        *(float4*)(ob + hw) = v;
    }
}

// ======================= round-7 middle tier =======================

__global__ void k_prep_e2(const float* __restrict__ emb, _Float16* __restrict__ es2,
                          float* __restrict__ out_loss) {
    int t = blockIdx.x * 256 + threadIdx.x;       // 17*32*64 = 34816
    if (t == 0) *out_loss = 0.f;
    if (t >= 17 * 32 * 64) return;
    int lane = t & 63;
    int cb   = (t >> 6) & 31;
    int akb  = t >> 11;                           // 0..16
    int m = cb * 32 + (lane & 31);
    int h = lane >> 5;
    _Float16 o[8];
    if (akb < 16) {
        #pragma unroll
        for (int j = 0; j < 8; ++j) {
            int c = akb * 16 + h * 8 + j;
            o[j] = (_Float16)(-2.0f * emb[m * EMBED_DIM + c]);
        }
    } else {
        #pragma unroll
        for (int j = 0; j < 8; ++j) o[j] = (_Float16)0.f;
        if (h == 0) {
            const float4* row = (const float4*)(emb + (size_t)m * EMBED_DIM);
            float nm = SBIAS;
            #pragma unroll 8
            for (int r = 0; r < 64; ++r) {
                float4 v = row[r];
                nm += v.x * v.x + v.y * v.y + v.z * v.z + v.w * v.w;
            }
            _Float16 nh = (_Float16)nm;
            _Float16 nl = (_Float16)(nm - (float)nh);
            o[0] = nh; o[1] = nl;
        }
    }
    *(h8v*)(es2 + (size_t)t * 8) = *(h8v*)o;
}

__global__ __launch_bounds__(512, 2)
void k_screen3(const float* __restrict__ z, const _Float16* __restrict__ es2,
               int4* __restrict__ cand) {
    __shared__ __align__(16) char abuf[2 * CHUNK_BYTES];

    const int tid  = threadIdx.x;
    const int lane = tid & 63;
    const int wv   = tid >> 6;
    const int pxl  = lane & 31;
    const int h    = lane >> 5;
    const int ln16 = lane * 16;

    {
        char* bufn = abuf;
        for (int f = wv; f < 34; f += 8) {
            const _Float16* src = es2 + ((size_t)((f >> 1) * 32 + (f & 1)) * 64 + lane) * 8;
            async16(src, bufn + f * 1024 + ln16);
        }
    }

    const int px = blockIdx.x * 256 + wv * 32 + pxl;
    const int b = px >> 12, hw = px & 4095;
    const float* zb = z + (size_t)b * (EMBED_DIM * HW) + hw;

    float nx = 0.f;
    h8v bx[32];
    #pragma unroll
    for (int kh = 0; kh < 16; ++kh) {
        const int c0 = kh * 16 + h * 8;
        _Float16 oh[8], ol[8];
        #pragma unroll
        for (int j = 0; j < 8; ++j) {
            float v = zb[(size_t)(c0 + j) * HW];
            nx += v * v;
            _Float16 hv = (_Float16)v;
            oh[j] = hv;
            ol[j] = (_Float16)(v - (float)hv);
        }
        bx[kh]      = *(h8v*)oh;
        bx[16 + kh] = *(h8v*)ol;
    }
    nx += __shfl_xor(nx, 32, 64);

    h8v bn;
    #pragma unroll
    for (int j = 0; j < 8; ++j) bn[j] = (_Float16)0.f;
    if (lane < 32) { bn[0] = (_Float16)1.f; bn[1] = (_Float16)1.f; }

    const int h4 = h * 4;
    unsigned b1 = 0xFFFFFFFFu, b2 = 0xFFFFFFFFu, b3 = 0xFFFFFFFFu;

    __syncthreads();

    for (int c = 0; c < 16; ++c) {
        if (c + 1 < 16) {
            char* bufn = abuf + ((c + 1) & 1) * CHUNK_BYTES;
            for (int f = wv; f < 34; f += 8) {
                const _Float16* src = es2 +
                    ((size_t)((f >> 1) * 32 + (c + 1) * 2 + (f & 1)) * 64 + lane) * 8;
                async16(src, bufn + f * 1024 + ln16);
            }
        }

        const char* bufc = abuf + (c & 1) * CHUNK_BYTES;
        f32x16 acc0, acc1;
        #pragma unroll
        for (int r = 0; r < 16; ++r) { acc0[r] = 0.f; acc1[r] = 0.f; }

        h8v a0 = *(const h8v*)(bufc + 0 * 1024 + ln16);
        h8v a1 = *(const h8v*)(bufc + 1 * 1024 + ln16);
        #pragma unroll
        for (int akb = 0; akb < 16; ++akb) {
            h8v n0 = *(const h8v*)(bufc + ((akb + 1) * 2 + 0) * 1024 + ln16);
            h8v n1 = *(const h8v*)(bufc + ((akb + 1) * 2 + 1) * 1024 + ln16);
            acc0 = __builtin_amdgcn_mfma_f32_32x32x16_f16(a0, bx[akb], acc0, 0, 0, 0);
            acc1 = __builtin_amdgcn_mfma_f32_32x32x16_f16(a1, bx[akb], acc1, 0, 0, 0);
            acc0 = __builtin_amdgcn_mfma_f32_32x32x16_f16(a0, bx[16 + akb], acc0, 0, 0, 0);
            acc1 = __builtin_amdgcn_mfma_f32_32x32x16_f16(a1, bx[16 + akb], acc1, 0, 0, 0);
            a0 = n0; a1 = n1;
        }
        acc0 = __builtin_amdgcn_mfma_f32_32x32x16_f16(a0, bn, acc0, 0, 0, 0);
        acc1 = __builtin_amdgcn_mfma_f32_32x32x16_f16(a1, bn, acc1, 0, 0, 0);

        const unsigned jb = (unsigned)(c * 64 + h4);
        #pragma unroll
        for (int r = 0; r < 16; ++r) {
            const unsigned row = (unsigned)((r & 3) + 8 * (r >> 2));
            unsigned u0 = (__float_as_uint(acc0[r]) & 0xFFFFFC00u) | (jb + row);
            unsigned u1 = (__float_as_uint(acc1[r]) & 0xFFFFFC00u) | (jb + row + 32u);
            top3_ins(u0, b1, b2, b3);
            top3_ins(u1, b1, b2, b3);
        }

        __syncthreads();
    }

    {
        unsigned o1 = __shfl_xor(b1, 32, 64);
        unsigned o2 = __shfl_xor(b2, 32, 64);
        unsigned o3 = __shfl_xor(b3, 32, 64);
        top3_ins(o1, b1, b2, b3);
        top3_ins(o2, b1, b2, b3);
        top3_ins(o3, b1, b2, b3);
    }

    if (lane < 32) {
        float s1 = __uint_as_float(b1 & 0xFFFFFC00u);
        float s2 = __uint_as_float(b2 & 0xFFFFFC00u);
        int  flag = (s2 - s1 < TAU) ? 0x10000 : 0;
        float d  = s1 - SBIAS + nx;
        cand[px] = make_int4((int)(b1 & 1023u),
                             (int)((b2 & 1023u) | flag),
                             (int)(b3 & 1023u),
                             __float_as_int(d));
    }
}

__global__ __launch_bounds__(256)
void k_epi2(const float* __restrict__ z, const float* __restrict__ emb,
            const int4* __restrict__ cand, float* __restrict__ out,
            float* __restrict__ out_loss) {
    const int tid   = threadIdx.x;
    const int lane  = tid & 63;
    const int pxblk = blockIdx.x >> 2;
    const int cq    = blockIdx.x & 3;
    const int px = pxblk * 256 + tid;
    const int b = px >> 12, hw = px & 4095;

    const int4 cd = cand[px];
    int   j = cd.x;
    float d = __int_as_float(cd.w);

    unsigned long long fm = __ballot((cd.y & 0x10000) != 0);
    if (fm) {
        const int pxw = pxblk * 256 + (tid & ~63);
        while (fm) {
            const int l = __ffsll(fm) - 1;
            fm &= fm - 1;
            const int fj1 = __shfl(cd.x, l, 64);
            const int fj2 = __shfl(cd.y, l, 64) & 1023;
            const int fj3 = __shfl(cd.z, l, 64);
            const int fpx = pxw + l;
            const float* zp = z + (size_t)(fpx >> 12) * (EMBED_DIM * HW) + (fpx & 4095);
            const int c0 = lane * 4;
            const float4 e1 = *(const float4*)(emb + (size_t)fj1 * EMBED_DIM + c0);
            const float4 e2 = *(const float4*)(emb + (size_t)fj2 * EMBED_DIM + c0);
            const float4 e3 = *(const float4*)(emb + (size_t)fj3 * EMBED_DIM + c0);
            float d1 = 0.f, d2 = 0.f, d3 = 0.f;
            #pragma unroll
            for (int k = 0; k < 4; ++k) {
                const float zv = zp[(size_t)(c0 + k) * HW];
                float t1 = ((const float*)&e1)[k] - zv; d1 += t1 * t1;
                float t2 = ((const float*)&e2)[k] - zv; d2 += t2 * t2;
                float t3 = ((const float*)&e3)[k] - zv; d3 += t3 * t3;
            }
            #pragma unroll
            for (int off = 32; off; off >>= 1) {
                d1 += __shfl_xor(d1, off, 64);
                d2 += __shfl_xor(d2, off, 64);
                d3 += __shfl_xor(d3, off, 64);
            }
            int bj = fj1; float bd = d1;
            if (d2 < bd || (d2 == bd && fj2 < bj)) { bd = d2; bj = fj2; }
            if (d3 < bd || (d3 == bd && fj3 < bj)) { bd = d3; bj = fj3; }
            if (lane == l) { j = bj; d = bd; }
        }
    }

    const float* er = emb + (size_t)j * EMBED_DIM + cq * 64;
    float* ob = out + (size_t)b * (EMBED_DIM * HW) + (size_t)(cq * 64) * HW + hw;
    #pragma unroll
    for (int q = 0; q < 16; ++q) {
        const float4 e4 = *(const float4*)(er + q * 4);
        ob[(size_t)(q * 4 + 0) * HW] = e4.x;
        ob[(size_t)(q * 4 + 1) * HW] = e4.y;
        ob[(size_t)(q * 4 + 2) * HW] = e4.z;
        ob[(size_t)(q * 4 + 3) * HW] = e4.w;
    }

    if (cq == 0) {
        float ls = d;
        #pragma unroll
        for (int off = 32; off; off >>= 1) ls += __shfl_xor(ls, off, 64);
        if (lane == 0)
            atomicAdd(out_loss, ls * (BETA / (float)NPIX / (float)EMBED_DIM));
    }
}

// ======================= fallback (round-1 fp32 path) =======================

__global__ void k_norms(const float* __restrict__ emb, float* __restrict__ norms,
                        float* __restrict__ loss_acc) {
    int j = blockIdx.x;
    int lane = threadIdx.x;
    const float* row = emb + j * EMBED_DIM;
    float s = 0.f;
    #pragma unroll
    for (int r = 0; r < 4; ++r) { float v = row[lane + r * 64]; s += v * v; }
    #pragma unroll
    for (int off = 32; off; off >>= 1) s += __shfl_down(s, off, 64);
    if (lane == 0) norms[j] = s;
    if (blockIdx.x == 0 && lane == 0) loss_acc[0] = 0.f;
}

__global__ void k_final(const float* __restrict__ loss_acc, float* __restrict__ out_loss) {
    *out_loss = (BETA / (float)NPIX / (float)EMBED_DIM) * (*loss_acc);
}

__global__ void k_transpose(const float* __restrict__ emb, float* __restrict__ et) {
    int idx = blockIdx.x * blockDim.x + threadIdx.x;
    int c = idx >> 10;
    int j = idx & 1023;
    et[idx] = -2.0f * emb[j * EMBED_DIM + c];
}

__global__ __launch_bounds__(256, 2)
void k_vq(const float* __restrict__ z, const float* __restrict__ emb,
          const float* __restrict__ et, const float* __restrict__ norms,
          float* __restrict__ out, float* __restrict__ loss_acc)
{
    __shared__ float zt[EMBED_DIM * 64];
    __shared__ float redv[16 * 64];
    __shared__ int   redi[16 * 64];
    __shared__ int   widx[64];
    __shared__ float wsum[4];
    const int tid = threadIdx.x;
    const int wg  = blockIdx.x;
    const int p0  = wg * 64;
    const int b   = p0 >> 12;
    const int hw0 = p0 & 4095;
    const float* zbase = z + (size_t)b * (EMBED_DIM * HW) + hw0;
    {
        const int lane16 = tid & 15;
        const int crow   = tid >> 4;
        #pragma unroll
        for (int r = 0; r < 16; ++r) {
            int c = r * 16 + crow;
            float4 vv = *(const float4*)(zbase + (size_t)c * HW + lane16 * 4);
            *(float4*)&zt[c * 64 + lane16 * 4] = vv;
        }
    }
    __syncthreads();
    const int pxg = tid & 15;
    const int cg  = tid >> 4;
    float bestv[4] = {3.4e38f, 3.4e38f, 3.4e38f, 3.4e38f};
    int   besti[4] = {0, 0, 0, 0};
    for (int chunk = 0; chunk < 16; ++chunk) {
        const int jbase = chunk * 64 + cg * 4;
        float acc[4][4];
        #pragma unroll
        for (int i = 0; i < 4; ++i)
            #pragma unroll
            for (int k = 0; k < 4; ++k) acc[i][k] = 0.f;
        const float* ec = et + jbase;
        #pragma unroll 4
        for (int c = 0; c < EMBED_DIM; ++c) {
            float4 za = *(const float4*)&zt[c * 64 + pxg * 4];
            float4 eb = *(const float4*)(ec + (size_t)c * N_EMBED);
            float zi[4] = {za.x, za.y, za.z, za.w};
            float ek[4] = {eb.x, eb.y, eb.z, eb.w};
            #pragma unroll
            for (int i = 0; i < 4; ++i)
                #pragma unroll
                for (int k = 0; k < 4; ++k)
                    acc[i][k] += zi[i] * ek[k];
        }
        float nn[4];
        #pragma unroll
        for (int k = 0; k < 4; ++k) nn[k] = norms[jbase + k];
        #pragma unroll
        for (int i = 0; i < 4; ++i)
            #pragma unroll
            for (int k = 0; k < 4; ++k) {
                float s = nn[k] + acc[i][k];
                if (s < bestv[i]) { bestv[i] = s; besti[i] = jbase + k; }
            }
    }
    #pragma unroll
    for (int i = 0; i < 4; ++i) {
        redv[cg * 64 + pxg * 4 + i] = bestv[i];
        redi[cg * 64 + pxg * 4 + i] = besti[i];
    }
    __syncthreads();
    if (tid < 64) {
        const int px2 = tid;
        float bv = redv[px2];
        int   bi = redi[px2];
        #pragma unroll
        for (int g = 1; g < 16; ++g) {
            float vv = redv[g * 64 + px2];
            int   ix = redi[g * 64 + px2];
            if (vv < bv || (vv == bv && ix < bi)) { bv = vv; bi = ix; }
        }
        widx[px2] = bi;
    }
    __syncthreads();
    const int px = tid & 63;
    const int wv = tid >> 6;
    const int j  = widx[px];
    const float* qrow = emb + (size_t)j * EMBED_DIM;
    float* obase = out + (size_t)b * (EMBED_DIM * HW) + hw0;
    float lsum = 0.f;
    #pragma unroll 4
    for (int cc = 0; cc < 16; ++cc) {
        const int c0 = wv * 64 + cc * 4;
        float4 q = *(const float4*)(qrow + c0);
        float qv[4] = {q.x, q.y, q.z, q.w};
        #pragma unroll
        for (int k = 0; k < 4; ++k) {
            const int c = c0 + k;
            float zv = zt[c * 64 + px];
            float d = qv[k] - zv;
            lsum += d * d;
            obase[(size_t)c * HW + px] = qv[k];
        }
    }
    #pragma unroll
    for (int off = 32; off; off >>= 1) lsum += __shfl_down(lsum, off, 64);
    if ((tid & 63) == 0) wsum[wv] = lsum;
    __syncthreads();
    if (tid == 0) atomicAdd(loss_acc, wsum[0] + wsum[1] + wsum[2] + wsum[3]);
}

// ======================= launch =======================

extern "C" void kernel_launch(void* const* d_in, const int* in_sizes, int n_in,
                              void* d_out, int out_size, void* d_ws, size_t ws_size,
                              hipStream_t stream) {
    const float* z   = (const float*)d_in[0];
    const float* emb = (const float*)d_in[1];
    float* out       = (float*)d_out;
    float* ws        = (float*)d_ws;

    if (ws_size >= NEED2_BYTES) {
        int4*           cand2    = (int4*)(ws + NW_CAND2);
        _Float16*       es2      = (_Float16*)(ws + NW_ES2B);
        unsigned short* widx     = (unsigned short*)(ws + NW_WIDX);
        float*          embT     = ws + NW_EMBT;
        float*          out_loss = out + (size_t)NPIX * EMBED_DIM;

        k_prep2<<<1160, 256, 0, stream>>>(emb, es2, embT, out_loss);
        k_screen5<<<512, 512, 0, stream>>>(z, es2, cand2);
        k_res<<<256, 256, 0, stream>>>(z, emb, cand2, widx, out_loss);
        k_epi3<<<1024, 256, 0, stream>>>(embT, widx, out);
    } else if (ws_size >= NEED_BYTES) {
        int4*      cand     = (int4*)(ws + NW_CAND);
        _Float16*  es2      = (_Float16*)(ws + NW_ES2);
        float*     out_loss = out + (size_t)NPIX * EMBED_DIM;

        k_prep_e2<<<136, 256, 0, stream>>>(emb, es2, out_loss);
        k_screen3<<<256, 512, 0, stream>>>(z, es2, cand);
        k_epi2<<<1024, 256, 0, stream>>>(z, emb, cand, out, out_loss);
    } else {
        float* loss_acc = ws;
        float* et       = ws + WS_ET_OFF;
        float* norms    = ws + WS_NORM_OFF;
        k_transpose<<<(EMBED_DIM * N_EMBED) / 256, 256, 0, stream>>>(emb, et);
        k_norms<<<N_EMBED, 64, 0, stream>>>(emb, norms, loss_acc);
        k_vq<<<NPIX / 64, 256, 0, stream>>>(z, emb, et, norms, out, loss_acc);
        k_final<<<1, 1, 0, stream>>>(loss_acc, out + (size_t)NPIX * EMBED_DIM);
    }
}

// Round 4
// 190.154 us; speedup vs baseline: 1.2139x; 1.0386x over previous
//
#include <hip/hip_runtime.h>
#include <hip/hip_bf16.h>

// VQ-VAE VectorQuantizer — round 9: counted-vmcnt screen pipeline.
//   k_prep2  : es2 A-frags (fp16 -2e + norm/bias kb) + embT[c][j] transpose.
//   k_screen6: code-split screen (512 blocks = 256 pxblk x 2 halves), hi-only
//              fp16 x. T3/T4 pipeline: each wave stages EXACTLY 5 frags/chunk
//              (34 real + benign dup), s_waitcnt vmcnt(5) + raw s_barrier —
//              staging loads stay in flight across barriers (no vmcnt(0)
//              drain until the last chunk). Packed top-3 per half.
//   k_res    : merge halves, flag gap<TAU, exact rescore flagged px (only z
//              reads), emit u16 widx + loss. 512x128 for latency hiding.
//   k_epi4   : one wave per out row (b,c): embT row staged in LDS, random
//              gathers via ds_read (not L1), contiguous float4 row stores.

#define EMBED_DIM 256
#define N_EMBED   1024
#define HW        4096
#define NPIX      65536
#define BETA      0.25f
#define SBIAS     1024.0f
#define TAU       0.375f

typedef _Float16 h8v __attribute__((ext_vector_type(8)));
typedef __attribute__((ext_vector_type(16))) float f32x16;

// ---------------- new-path workspace layout (float offsets) ----------------
#define NW_CAND2  1152            // 2*65536 int4 = 524288 floats
#define NW_ES2B   525440          // 17*32*64 h8v = 139264 floats
#define NW_WIDX   525440          // u16[65536] aliases es2 (dead after screen)
#define NW_EMBT   664704          // 256*1024 floats
#define NW_END2   926848
#define NEED2_BYTES ((size_t)NW_END2 * 4)

// ---------------- round-7 (middle tier) layout ----------------
#define NW_CAND   1152
#define NW_ES2    263296
#define NW_END    402560
#define NEED_BYTES ((size_t)NW_END * 4)

// fallback (round-1) layout
#define WS_ET_OFF    64
#define WS_NORM_OFF  (64 + EMBED_DIM * N_EMBED)

#define CHUNK_BYTES (34 * 1024)   // 17 akb x 2 cb x 1 KB per chunk of 64 codes

__device__ inline void async16(const void* g, void* s) {
    __builtin_amdgcn_global_load_lds(
        (const __attribute__((address_space(1))) unsigned int*)g,
        (__attribute__((address_space(3))) unsigned int*)s, 16, 0, 0);
}

__device__ inline unsigned umin2(unsigned a, unsigned b) { return a < b ? a : b; }
__device__ inline unsigned umax2(unsigned a, unsigned b) { return a < b ? b : a; }

// sorted top-3 insert on packed (score|idx) — pure min/max network
__device__ inline void top3_ins(unsigned u, unsigned& b1, unsigned& b2, unsigned& b3) {
    unsigned t0 = umax2(b1, u);  b1 = umin2(b1, u);
    unsigned t1 = umax2(b2, t0); b2 = umin2(b2, t0);
    b3 = umin2(b3, t1);
}

// ======================= prep kernel (new path) =======================

__global__ void k_prep2(const float* __restrict__ emb, _Float16* __restrict__ es2,
                        float* __restrict__ embT, float* __restrict__ out_loss) {
    if (blockIdx.x < 136) {
        int t = blockIdx.x * 256 + threadIdx.x;       // 0..34815
        if (t == 0) *out_loss = 0.f;
        int lane = t & 63;
        int cb   = (t >> 6) & 31;
        int akb  = t >> 11;                           // 0..16
        int m = cb * 32 + (lane & 31);
        int h = lane >> 5;
        _Float16 o[8];
        if (akb < 16) {
            #pragma unroll
            for (int j = 0; j < 8; ++j) {
                int c = akb * 16 + h * 8 + j;
                o[j] = (_Float16)(-2.0f * emb[m * EMBED_DIM + c]);
            }
        } else {
            #pragma unroll
            for (int j = 0; j < 8; ++j) o[j] = (_Float16)0.f;
            if (h == 0) {                             // inline norm
                const float4* row = (const float4*)(emb + (size_t)m * EMBED_DIM);
                float nm = SBIAS;
                #pragma unroll 8
                for (int r = 0; r < 64; ++r) {
                    float4 v = row[r];
                    nm += v.x * v.x + v.y * v.y + v.z * v.z + v.w * v.w;
                }
                _Float16 nh = (_Float16)nm;
                _Float16 nl = (_Float16)(nm - (float)nh);
                o[0] = nh; o[1] = nl;
            }
        }
        *(h8v*)(es2 + (size_t)t * 8) = *(h8v*)o;
    } else {
        int t2 = (blockIdx.x - 136) * 256 + threadIdx.x;   // 0..262143
        int j = t2 & 1023;
        int c = t2 >> 10;
        embT[t2] = emb[(size_t)j * EMBED_DIM + c];
    }
}

// ======================= screen kernel (counted-vmcnt) =======================
// 512 threads (8 waves). blockIdx = pxblk*2 + half; 8 chunks of 64 codes.
// Each wave stages exactly 5 frags/chunk (frag >= 34 wraps to a duplicate —
// identical bytes, benign). Pipeline depth 2: stage(c+2) issued after barB;
// vmcnt(5) before barA guarantees chunk c resident without draining c+1.

__global__ __launch_bounds__(512, 2)
void k_screen6(const float* __restrict__ z, const _Float16* __restrict__ es2,
               int4* __restrict__ cand2) {
    __shared__ __align__(16) char abuf[2 * CHUNK_BYTES];   // 68 KB

    const int tid  = threadIdx.x;
    const int lane = tid & 63;
    const int wv   = tid >> 6;                    // 0..7
    const int pxl  = lane & 31;
    const int h    = lane >> 5;
    const int ln16 = lane * 16;
    const int pxblk = blockIdx.x >> 1;
    const int half  = blockIdx.x & 1;
    const int gc0   = half * 8;                   // first global chunk

    int fr[5];                                    // this wave's 5 frag ids
    #pragma unroll
    for (int i = 0; i < 5; ++i) { int f = wv + i * 8; fr[i] = (f >= 34) ? f - 34 : f; }

    auto stage = [&](int gc, int buf) {
        char* bufn = abuf + buf * CHUNK_BYTES;
        #pragma unroll
        for (int i = 0; i < 5; ++i) {
            const int f = fr[i];
            const _Float16* src = es2 +
                ((size_t)((f >> 1) * 32 + gc * 2 + (f & 1)) * 64 + lane) * 8;
            async16(src, bufn + f * 1024 + ln16);
        }
    };

    stage(gc0 + 0, 0);
    stage(gc0 + 1, 1);

    // build B fragments (hi-only) from z; accumulate ||x||^2.
    // NOTE: these loads are younger than the staging loads, so the compiler's
    // waits on their uses also drain stage(0)/stage(1) — harmless (prologue).
    const int px = pxblk * 256 + wv * 32 + pxl;
    const int b = px >> 12, hw = px & 4095;
    const float* zb = z + (size_t)b * (EMBED_DIM * HW) + hw;

    float nx = 0.f;
    h8v bx[16];
    #pragma unroll
    for (int kh = 0; kh < 16; ++kh) {
        const int c0 = kh * 16 + h * 8;
        _Float16 oh[8];
        #pragma unroll
        for (int j = 0; j < 8; ++j) {
            float v = zb[(size_t)(c0 + j) * HW];
            nx += v * v;
            oh[j] = (_Float16)v;
        }
        bx[kh] = *(h8v*)oh;
    }
    nx += __shfl_xor(nx, 32, 64);                 // full ||x||^2 on both halves

    h8v bn;                                       // norm-kb B: B[0..1][n] = 1
    #pragma unroll
    for (int j = 0; j < 8; ++j) bn[j] = (_Float16)0.f;
    if (lane < 32) { bn[0] = (_Float16)1.f; bn[1] = (_Float16)1.f; }

    const int h4 = h * 4;
    unsigned b1 = 0xFFFFFFFFu, b2 = 0xFFFFFFFFu, b3 = 0xFFFFFFFFu;

    for (int c = 0; c < 8; ++c) {
        // own stage(c) complete; stage(c+1) may stay in flight (except last)
        if (c == 7) { asm volatile("s_waitcnt vmcnt(0)" ::: "memory"); }
        else        { asm volatile("s_waitcnt vmcnt(5)" ::: "memory"); }
        __builtin_amdgcn_sched_barrier(0);
        __builtin_amdgcn_s_barrier();             // barA: all waves' chunk c in LDS
        __builtin_amdgcn_sched_barrier(0);

        const char* bufc = abuf + (c & 1) * CHUNK_BYTES;
        f32x16 acc0, acc1;
        #pragma unroll
        for (int r = 0; r < 16; ++r) { acc0[r] = 0.f; acc1[r] = 0.f; }

        h8v a0 = *(const h8v*)(bufc + 0 * 1024 + ln16);
        h8v a1 = *(const h8v*)(bufc + 1 * 1024 + ln16);
        __builtin_amdgcn_s_setprio(1);
        #pragma unroll
        for (int akb = 0; akb < 16; ++akb) {
            h8v n0 = *(const h8v*)(bufc + ((akb + 1) * 2 + 0) * 1024 + ln16);
            h8v n1 = *(const h8v*)(bufc + ((akb + 1) * 2 + 1) * 1024 + ln16);
            acc0 = __builtin_amdgcn_mfma_f32_32x32x16_f16(a0, bx[akb], acc0, 0, 0, 0);
            acc1 = __builtin_amdgcn_mfma_f32_32x32x16_f16(a1, bx[akb], acc1, 0, 0, 0);
            a0 = n0; a1 = n1;
        }
        acc0 = __builtin_amdgcn_mfma_f32_32x32x16_f16(a0, bn, acc0, 0, 0, 0);
        acc1 = __builtin_amdgcn_mfma_f32_32x32x16_f16(a1, bn, acc1, 0, 0, 0);
        __builtin_amdgcn_s_setprio(0);

        __builtin_amdgcn_sched_barrier(0);
        __builtin_amdgcn_s_barrier();             // barB: all waves done reading
        __builtin_amdgcn_sched_barrier(0);

        if (c + 2 < 8) stage(gc0 + c + 2, c & 1); // overwrite now-free buffer

        // top-3 update overlaps the in-flight staging
        const unsigned jb = (unsigned)((gc0 + c) * 64 + h4);
        #pragma unroll
        for (int r = 0; r < 16; ++r) {
            const unsigned row = (unsigned)((r & 3) + 8 * (r >> 2));
            unsigned u0 = (__float_as_uint(acc0[r]) & 0xFFFFFC00u) | (jb + row);
            unsigned u1 = (__float_as_uint(acc1[r]) & 0xFFFFFC00u) | (jb + row + 32u);
            top3_ins(u0, b1, b2, b3);
            top3_ins(u1, b1, b2, b3);
        }
    }

    // merge the two k-row halves (lane^32 holds the other 16 rows per block)
    {
        unsigned o1 = __shfl_xor(b1, 32, 64);
        unsigned o2 = __shfl_xor(b2, 32, 64);
        unsigned o3 = __shfl_xor(b3, 32, 64);
        top3_ins(o1, b1, b2, b3);
        top3_ins(o2, b1, b2, b3);
        top3_ins(o3, b1, b2, b3);
    }

    if (lane < 32)
        cand2[(half << 16) + px] =
            make_int4((int)b1, (int)b2, (int)b3, __float_as_int(nx));
}

// ======================= resolve kernel =======================
// Merge per-half top-3, flag gap<TAU, exact rescore flagged px (wave-coop),
// emit widx[px] (u16) + loss. 512 blocks x 128 threads (2 blocks/CU).

__global__ __launch_bounds__(128)
void k_res(const float* __restrict__ z, const float* __restrict__ emb,
           const int4* __restrict__ cand2, unsigned short* __restrict__ widx,
           float* __restrict__ out_loss) {
    __shared__ float wsum[2];
    const int tid  = threadIdx.x;
    const int lane = tid & 63;
    const int wv   = tid >> 6;
    const int px   = blockIdx.x * 128 + tid;

    const int4 A = cand2[px];
    const int4 B = cand2[65536 + px];

    unsigned m1 = 0xFFFFFFFFu, m2 = 0xFFFFFFFFu, m3 = 0xFFFFFFFFu;
    top3_ins((unsigned)A.x, m1, m2, m3);
    top3_ins((unsigned)A.y, m1, m2, m3);
    top3_ins((unsigned)A.z, m1, m2, m3);
    top3_ins((unsigned)B.x, m1, m2, m3);
    top3_ins((unsigned)B.y, m1, m2, m3);
    top3_ins((unsigned)B.z, m1, m2, m3);

    const float s1 = __uint_as_float(m1 & 0xFFFFFC00u);
    const float s2 = __uint_as_float(m2 & 0xFFFFFC00u);
    const float nx = __int_as_float(A.w);
    int   j = (int)(m1 & 1023u);
    float d = s1 - SBIAS + nx;                     // screen-accurate distance
    const int j2 = (int)(m2 & 1023u);
    const int j3 = (int)(m3 & 1023u);

    unsigned long long fm = __ballot(s2 - s1 < TAU);
    if (fm) {
        const int pxw = blockIdx.x * 128 + (tid & ~63);   // wave's first px
        while (fm) {
            const int l = __ffsll(fm) - 1;
            fm &= fm - 1;
            const int fj1 = __shfl(j, l, 64);
            const int fj2 = __shfl(j2, l, 64);
            const int fj3 = __shfl(j3, l, 64);
            const int fpx = pxw + l;
            const float* zp = z + (size_t)(fpx >> 12) * (EMBED_DIM * HW) + (fpx & 4095);
            const int c0 = lane * 4;
            const float4 e1 = *(const float4*)(emb + (size_t)fj1 * EMBED_DIM + c0);
            const float4 e2 = *(const float4*)(emb + (size_t)fj2 * EMBED_DIM + c0);
            const float4 e3 = *(const float4*)(emb + (size_t)fj3 * EMBED_DIM + c0);
            float d1 = 0.f, d2 = 0.f, d3 = 0.f;
            #pragma unroll
            for (int k = 0; k < 4; ++k) {
                const float zv = zp[(size_t)(c0 + k) * HW];
                float t1 = ((const float*)&e1)[k] - zv; d1 += t1 * t1;
                float t2 = ((const float*)&e2)[k] - zv; d2 += t2 * t2;
                float t3 = ((const float*)&e3)[k] - zv; d3 += t3 * t3;
            }
            #pragma unroll
            for (int off = 32; off; off >>= 1) {
                d1 += __shfl_xor(d1, off, 64);
                d2 += __shfl_xor(d2, off, 64);
                d3 += __shfl_xor(d3, off, 64);
            }
            int bj = fj1; float bd = d1;
            if (d2 < bd || (d2 == bd && fj2 < bj)) { bd = d2; bj = fj2; }
            if (d3 < bd || (d3 == bd && fj3 < bj)) { bd = d3; bj = fj3; }
            if (lane == l) { j = bj; d = bd; }
        }
    }

    widx[px] = (unsigned short)j;

    float ls = d;
    #pragma unroll
    for (int off = 32; off; off >>= 1) ls += __shfl_xor(ls, off, 64);
    if (lane == 0) wsum[wv] = ls;
    __syncthreads();
    if (tid == 0)
        atomicAdd(out_loss, (wsum[0] + wsum[1]) *
                            (BETA / (float)NPIX / (float)EMBED_DIM));
}

// ======================= streaming epilogue =======================
// One wave per out row (b,c). embT row staged into LDS; random gathers hit
// LDS banks (~10 cyc) instead of serializing in L1. Contiguous 16 KB stores.

__global__ __launch_bounds__(256)
void k_epi4(const float* __restrict__ embT, const unsigned short* __restrict__ widx,
            float* __restrict__ out) {
    __shared__ float etl[4][N_EMBED];             // 16 KB
    const int tid  = threadIdx.x;
    const int lane = tid & 63;
    const int wv   = tid >> 6;
    const int rowid = blockIdx.x * 4 + wv;        // 0..4095
    const int b = rowid >> 8;
    const int c = rowid & 255;

    const unsigned short* wb = widx + b * HW;
    const float4* et4 = (const float4*)(embT + (size_t)c * N_EMBED);
    float* ob = out + (size_t)b * (EMBED_DIM * HW) + (size_t)c * HW;

    #pragma unroll
    for (int i = 0; i < 4; ++i)                   // wave-private row stage
        *(float4*)&etl[wv][(lane + i * 64) * 4] = et4[lane + i * 64];

    #pragma unroll 4
    for (int t = 0; t < 16; ++t) {
        const int hw = t * 256 + lane * 4;
        const ushort4 jj = *(const ushort4*)(wb + hw);
        float4 v;
        v.x = etl[wv][jj.x];
        v.y = etl[wv][jj.y];
        v.z = etl[wv][jj.z];
        v.w = etl[wv][jj.w];
        *(float4*)(ob + hw) = v;
    }
}

// ======================= round-7 middle tier =======================

__global__ void k_prep_e2(const float* __restrict__ emb, _Float16* __restrict__ es2,
                          float* __restrict__ out_loss) {
    int t = blockIdx.x * 256 + threadIdx.x;       // 17*32*64 = 34816
    if (t == 0) *out_loss = 0.f;
    if (t >= 17 * 32 * 64) return;
    int lane = t & 63;
    int cb   = (t >> 6) & 31;
    int akb  = t >> 11;                           // 0..16
    int m = cb * 32 + (lane & 31);
    int h = lane >> 5;
    _Float16 o[8];
    if (akb < 16) {
        #pragma unroll
        for (int j = 0; j < 8; ++j) {
            int c = akb * 16 + h * 8 + j;
            o[j] = (_Float16)(-2.0f * emb[m * EMBED_DIM + c]);
        }
    } else {
        #pragma unroll
        for (int j = 0; j < 8; ++j) o[j] = (_Float16)0.f;
        if (h == 0) {
            const float4* row = (const float4*)(emb + (size_t)m * EMBED_DIM);
            float nm = SBIAS;
            #pragma unroll 8
            for (int r = 0; r < 64; ++r) {
                float4 v = row[r];
                nm += v.x * v.x + v.y * v.y + v.z * v.z + v.w * v.w;
            }
            _Float16 nh = (_Float16)nm;
            _Float16 nl = (_Float16)(nm - (float)nh);
            o[0] = nh; o[1] = nl;
        }
    }
    *(h8v*)(es2 + (size_t)t * 8) = *(h8v*)o;
}

__global__ __launch_bounds__(512, 2)
void k_screen3(const float* __restrict__ z, const _Float16* __restrict__ es2,
               int4* __restrict__ cand) {
    __shared__ __align__(16) char abuf[2 * CHUNK_BYTES];

    const int tid  = threadIdx.x;
    const int lane = tid & 63;
    const int wv   = tid >> 6;
    const int pxl  = lane & 31;
    const int h    = lane >> 5;
    const int ln16 = lane * 16;

    {
        char* bufn = abuf;
        for (int f = wv; f < 34; f += 8) {
            const _Float16* src = es2 + ((size_t)((f >> 1) * 32 + (f & 1)) * 64 + lane) * 8;
            async16(src, bufn + f * 1024 + ln16);
        }
    }

    const int px = blockIdx.x * 256 + wv * 32 + pxl;
    const int b = px >> 12, hw = px & 4095;
    const float* zb = z + (size_t)b * (EMBED_DIM * HW) + hw;

    float nx = 0.f;
    h8v bx[32];
    #pragma unroll
    for (int kh = 0; kh < 16; ++kh) {
        const int c0 = kh * 16 + h * 8;
        _Float16 oh[8], ol[8];
        #pragma unroll
        for (int j = 0; j < 8; ++j) {
            float v = zb[(size_t)(c0 + j) * HW];
            nx += v * v;
            _Float16 hv = (_Float16)v;
            oh[j] = hv;
            ol[j] = (_Float16)(v - (float)hv);
        }
        bx[kh]      = *(h8v*)oh;
        bx[16 + kh] = *(h8v*)ol;
    }
    nx += __shfl_xor(nx, 32, 64);

    h8v bn;
    #pragma unroll
    for (int j = 0; j < 8; ++j) bn[j] = (_Float16)0.f;
    if (lane < 32) { bn[0] = (_Float16)1.f; bn[1] = (_Float16)1.f; }

    const int h4 = h * 4;
    unsigned b1 = 0xFFFFFFFFu, b2 = 0xFFFFFFFFu, b3 = 0xFFFFFFFFu;

    __syncthreads();

    for (int c = 0; c < 16; ++c) {
        if (c + 1 < 16) {
            char* bufn = abuf + ((c + 1) & 1) * CHUNK_BYTES;
            for (int f = wv; f < 34; f += 8) {
                const _Float16* src = es2 +
                    ((size_t)((f >> 1) * 32 + (c + 1) * 2 + (f & 1)) * 64 + lane) * 8;
                async16(src, bufn + f * 1024 + ln16);
            }
        }

        const char* bufc = abuf + (c & 1) * CHUNK_BYTES;
        f32x16 acc0, acc1;
        #pragma unroll
        for (int r = 0; r < 16; ++r) { acc0[r] = 0.f; acc1[r] = 0.f; }

        h8v a0 = *(const h8v*)(bufc + 0 * 1024 + ln16);
        h8v a1 = *(const h8v*)(bufc + 1 * 1024 + ln16);
        #pragma unroll
        for (int akb = 0; akb < 16; ++akb) {
            h8v n0 = *(const h8v*)(bufc + ((akb + 1) * 2 + 0) * 1024 + ln16);
            h8v n1 = *(const h8v*)(bufc + ((akb + 1) * 2 + 1) * 1024 + ln16);
            acc0 = __builtin_amdgcn_mfma_f32_32x32x16_f16(a0, bx[akb], acc0, 0, 0, 0);
            acc1 = __builtin_amdgcn_mfma_f32_32x32x16_f16(a1, bx[akb], acc1, 0, 0, 0);
            acc0 = __builtin_amdgcn_mfma_f32_32x32x16_f16(a0, bx[16 + akb], acc0, 0, 0, 0);
            acc1 = __builtin_amdgcn_mfma_f32_32x32x16_f16(a1, bx[16 + akb], acc1, 0, 0, 0);
            a0 = n0; a1 = n1;
        }
        acc0 = __builtin_amdgcn_mfma_f32_32x32x16_f16(a0, bn, acc0, 0, 0, 0);
        acc1 = __builtin_amdgcn_mfma_f32_32x32x16_f16(a1, bn, acc1, 0, 0, 0);

        const unsigned jb = (unsigned)(c * 64 + h4);
        #pragma unroll
        for (int r = 0; r < 16; ++r) {
            const unsigned row = (unsigned)((r & 3) + 8 * (r >> 2));
            unsigned u0 = (__float_as_uint(acc0[r]) & 0xFFFFFC00u) | (jb + row);
            unsigned u1 = (__float_as_uint(acc1[r]) & 0xFFFFFC00u) | (jb + row + 32u);
            top3_ins(u0, b1, b2, b3);
            top3_ins(u1, b1, b2, b3);
        }

        __syncthreads();
    }

    {
        unsigned o1 = __shfl_xor(b1, 32, 64);
        unsigned o2 = __shfl_xor(b2, 32, 64);
        unsigned o3 = __shfl_xor(b3, 32, 64);
        top3_ins(o1, b1, b2, b3);
        top3_ins(o2, b1, b2, b3);
        top3_ins(o3, b1, b2, b3);
    }

    if (lane < 32) {
        float s1 = __uint_as_float(b1 & 0xFFFFFC00u);
        float s2 = __uint_as_float(b2 & 0xFFFFFC00u);
        int  flag = (s2 - s1 < TAU) ? 0x10000 : 0;
        float d  = s1 - SBIAS + nx;
        cand[px] = make_int4((int)(b1 & 1023u),
                             (int)((b2 & 1023u) | flag),
                             (int)(b3 & 1023u),
                             __float_as_int(d));
    }
}

__global__ __launch_bounds__(256)
void k_epi2(const float* __restrict__ z, const float* __restrict__ emb,
            const int4* __restrict__ cand, float* __restrict__ out,
            float* __restrict__ out_loss) {
    const int tid   = threadIdx.x;
    const int lane  = tid & 63;
    const int pxblk = blockIdx.x >> 2;
    const int cq    = blockIdx.x & 3;
    const int px = pxblk * 256 + tid;
    const int b = px >> 12, hw = px & 4095;

    const int4 cd = cand[px];
    int   j = cd.x;
    float d = __int_as_float(cd.w);

    unsigned long long fm = __ballot((cd.y & 0x10000) != 0);
    if (fm) {
        const int pxw = pxblk * 256 + (tid & ~63);
        while (fm) {
            const int l = __ffsll(fm) - 1;
            fm &= fm - 1;
            const int fj1 = __shfl(cd.x, l, 64);
            const int fj2 = __shfl(cd.y, l, 64) & 1023;
            const int fj3 = __shfl(cd.z, l, 64);
            const int fpx = pxw + l;
            const float* zp = z + (size_t)(fpx >> 12) * (EMBED_DIM * HW) + (fpx & 4095);
            const int c0 = lane * 4;
            const float4 e1 = *(const float4*)(emb + (size_t)fj1 * EMBED_DIM + c0);
            const float4 e2 = *(const float4*)(emb + (size_t)fj2 * EMBED_DIM + c0);
            const float4 e3 = *(const float4*)(emb + (size_t)fj3 * EMBED_DIM + c0);
            float d1 = 0.f, d2 = 0.f, d3 = 0.f;
            #pragma unroll
            for (int k = 0; k < 4; ++k) {
                const float zv = zp[(size_t)(c0 + k) * HW];
                float t1 = ((const float*)&e1)[k] - zv; d1 += t1 * t1;
                float t2 = ((const float*)&e2)[k] - zv; d2 += t2 * t2;
                float t3 = ((const float*)&e3)[k] - zv; d3 += t3 * t3;
            }
            #pragma unroll
            for (int off = 32; off; off >>= 1) {
                d1 += __shfl_xor(d1, off, 64);
                d2 += __shfl_xor(d2, off, 64);
                d3 += __shfl_xor(d3, off, 64);
            }
            int bj = fj1; float bd = d1;
            if (d2 < bd || (d2 == bd && fj2 < bj)) { bd = d2; bj = fj2; }
            if (d3 < bd || (d3 == bd && fj3 < bj)) { bd = d3; bj = fj3; }
            if (lane == l) { j = bj; d = bd; }
        }
    }

    const float* er = emb + (size_t)j * EMBED_DIM + cq * 64;
    float* ob = out + (size_t)b * (EMBED_DIM * HW) + (size_t)(cq * 64) * HW + hw;
    #pragma unroll
    for (int q = 0; q < 16; ++q) {
        const float4 e4 = *(const float4*)(er + q * 4);
        ob[(size_t)(q * 4 + 0) * HW] = e4.x;
        ob[(size_t)(q * 4 + 1) * HW] = e4.y;
        ob[(size_t)(q * 4 + 2) * HW] = e4.z;
        ob[(size_t)(q * 4 + 3) * HW] = e4.w;
    }

    if (cq == 0) {
        float ls = d;
        #pragma unroll
        for (int off = 32; off; off >>= 1) ls += __shfl_xor(ls, off, 64);
        if (lane == 0)
            atomicAdd(out_loss, ls * (BETA / (float)NPIX / (float)EMBED_DIM));
    }
}

// ======================= fallback (round-1 fp32 path) =======================

__global__ void k_norms(const float* __restrict__ emb, float* __restrict__ norms,
                        float* __restrict__ loss_acc) {
    int j = blockIdx.x;
    int lane = threadIdx.x;
    const float* row = emb + j * EMBED_DIM;
    float s = 0.f;
    #pragma unroll
    for (int r = 0; r < 4; ++r) { float v = row[lane + r * 64]; s += v * v; }
    #pragma unroll
    for (int off = 32; off; off >>= 1) s += __shfl_down(s, off, 64);
    if (lane == 0) norms[j] = s;
    if (blockIdx.x == 0 && lane == 0) loss_acc[0] = 0.f;
}

__global__ void k_final(const float* __restrict__ loss_acc, float* __restrict__ out_loss) {
    *out_loss = (BETA / (float)NPIX / (float)EMBED_DIM) * (*loss_acc);
}

__global__ void k_transpose(const float* __restrict__ emb, float* __restrict__ et) {
    int idx = blockIdx.x * blockDim.x + threadIdx.x;
    int c = idx >> 10;
    int j = idx & 1023;
    et[idx] = -2.0f * emb[j * EMBED_DIM + c];
}

__global__ __launch_bounds__(256, 2)
void k_vq(const float* __restrict__ z, const float* __restrict__ emb,
          const float* __restrict__ et, const float* __restrict__ norms,
          float* __restrict__ out, float* __restrict__ loss_acc)
{
    __shared__ float zt[EMBED_DIM * 64];
    __shared__ float redv[16 * 64];
    __shared__ int   redi[16 * 64];
    __shared__ int   widx[64];
    __shared__ float wsum[4];
    const int tid = threadIdx.x;
    const int wg  = blockIdx.x;
    const int p0  = wg * 64;
    const int b   = p0 >> 12;
    const int hw0 = p0 & 4095;
    const float* zbase = z + (size_t)b * (EMBED_DIM * HW) + hw0;
    {
        const int lane16 = tid & 15;
        const int crow   = tid >> 4;
        #pragma unroll
        for (int r = 0; r < 16; ++r) {
            int c = r * 16 + crow;
            float4 vv = *(const float4*)(zbase + (size_t)c * HW + lane16 * 4);
            *(float4*)&zt[c * 64 + lane16 * 4] = vv;
        }
    }
    __syncthreads();
    const int pxg = tid & 15;
    const int cg  = tid >> 4;
    float bestv[4] = {3.4e38f, 3.4e38f, 3.4e38f, 3.4e38f};
    int   besti[4] = {0, 0, 0, 0};
    for (int chunk = 0; chunk < 16; ++chunk) {
        const int jbase = chunk * 64 + cg * 4;
        float acc[4][4];
        #pragma unroll
        for (int i = 0; i < 4; ++i)
            #pragma unroll
            for (int k = 0; k < 4; ++k) acc[i][k] = 0.f;
        const float* ec = et + jbase;
        #pragma unroll 4
        for (int c = 0; c < EMBED_DIM; ++c) {
            float4 za = *(const float4*)&zt[c * 64 + pxg * 4];
            float4 eb = *(const float4*)(ec + (size_t)c * N_EMBED);
            float zi[4] = {za.x, za.y, za.z, za.w};
            float ek[4] = {eb.x, eb.y, eb.z, eb.w};
            #pragma unroll
            for (int i = 0; i < 4; ++i)
                #pragma unroll
                for (int k = 0; k < 4; ++k)
                    acc[i][k] += zi[i] * ek[k];
        }
        float nn[4];
        #pragma unroll
        for (int k = 0; k < 4; ++k) nn[k] = norms[jbase + k];
        #pragma unroll
        for (int i = 0; i < 4; ++i)
            #pragma unroll
            for (int k = 0; k < 4; ++k) {
                float s = nn[k] + acc[i][k];
                if (s < bestv[i]) { bestv[i] = s; besti[i] = jbase + k; }
            }
    }
    #pragma unroll
    for (int i = 0; i < 4; ++i) {
        redv[cg * 64 + pxg * 4 + i] = bestv[i];
        redi[cg * 64 + pxg * 4 + i] = besti[i];
    }
    __syncthreads();
    if (tid < 64) {
        const int px2 = tid;
        float bv = redv[px2];
        int   bi = redi[px2];
        #pragma unroll
        for (int g = 1; g < 16; ++g) {
            float vv = redv[g * 64 + px2];
            int   ix = redi[g * 64 + px2];
            if (vv < bv || (vv == bv && ix < bi)) { bv = vv; bi = ix; }
        }
        widx[px2] = bi;
    }
    __syncthreads();
    const int px = tid & 63;
    const int wv = tid >> 6;
    const int j  = widx[px];
    const float* qrow = emb + (size_t)j * EMBED_DIM;
    float* obase = out + (size_t)b * (EMBED_DIM * HW) + hw0;
    float lsum = 0.f;
    #pragma unroll 4
    for (int cc = 0; cc < 16; ++cc) {
        const int c0 = wv * 64 + cc * 4;
        float4 q = *(const float4*)(qrow + c0);
        float qv[4] = {q.x, q.y, q.z, q.w};
        #pragma unroll
        for (int k = 0; k < 4; ++k) {
            const int c = c0 + k;
            float zv = zt[c * 64 + px];
            float d = qv[k] - zv;
            lsum += d * d;
            obase[(size_t)c * HW + px] = qv[k];
        }
    }
    #pragma unroll
    for (int off = 32; off; off >>= 1) lsum += __shfl_down(lsum, off, 64);
    if ((tid & 63) == 0) wsum[wv] = lsum;
    __syncthreads();
    if (tid == 0) atomicAdd(loss_acc, wsum[0] + wsum[1] + wsum[2] + wsum[3]);
}

// ======================= launch =======================

extern "C" void kernel_launch(void* const* d_in, const int* in_sizes, int n_in,
                              void* d_out, int out_size, void* d_ws, size_t ws_size,
                              hipStream_t stream) {
    const float* z   = (const float*)d_in[0];
    const float* emb = (const float*)d_in[1];
    float* out       = (float*)d_out;
    float* ws        = (float*)d_ws;

    if (ws_size >= NEED2_BYTES) {
        int4*           cand2    = (int4*)(ws + NW_CAND2);
        _Float16*       es2      = (_Float16*)(ws + NW_ES2B);
        unsigned short* widx     = (unsigned short*)(ws + NW_WIDX);
        float*          embT     = ws + NW_EMBT;
        float*          out_loss = out + (size_t)NPIX * EMBED_DIM;

        k_prep2<<<1160, 256, 0, stream>>>(emb, es2, embT, out_loss);
        k_screen6<<<512, 512, 0, stream>>>(z, es2, cand2);
        k_res<<<512, 128, 0, stream>>>(z, emb, cand2, widx, out_loss);
        k_epi4<<<1024, 256, 0, stream>>>(embT, widx, out);
    } else if (ws_size >= NEED_BYTES) {
        int4*      cand     = (int4*)(ws + NW_CAND);
        _Float16*  es2      = (_Float16*)(ws + NW_ES2);
        float*     out_loss = out + (size_t)NPIX * EMBED_DIM;

        k_prep_e2<<<136, 256, 0, stream>>>(emb, es2, out_loss);
        k_screen3<<<256, 512, 0, stream>>>(z, es2, cand);
        k_epi2<<<1024, 256, 0, stream>>>(z, emb, cand, out, out_loss);
    } else {
        float* loss_acc = ws;
        float* et       = ws + WS_ET_OFF;
        float* norms    = ws + WS_NORM_OFF;
        k_transpose<<<(EMBED_DIM * N_EMBED) / 256, 256, 0, stream>>>(emb, et);
        k_norms<<<N_EMBED, 64, 0, stream>>>(emb, norms, loss_acc);
        k_vq<<<NPIX / 64, 256, 0, stream>>>(z, emb, et, norms, out, loss_acc);
        k_final<<<1, 1, 0, stream>>>(loss_acc, out + (size_t)NPIX * EMBED_DIM);
    }
}